// Round 1
// baseline (363.110 us; speedup 1.0000x reference)
//
#include <hip/hip_runtime.h>
#include <hip/hip_bf16.h>

// FrequencyAttention restructured:
//   G = X X^T (per batch, 64x64)            -> k_gram (+ k_reduceG)
//   T1 = inv_q * (Wq G); norms via diag     -> k_rows
//   att = softmax(T1 Wk^T * inv_k); M=att Wv-> k_att
//   out = M X                               -> k_out
// Shapes: B=4, C=64, N=102400, D=64. W rows: [0:64]=Wq, [64:128]=Wk, [128:192]=Wv.

#define BATCH 4
#define CH 64
#define NTOK 102400
#define DIM 64

#define GRAM_BLOCKS_PER_B 64   // 64 blocks/batch * 1600 tokens each
#define OUT_BLOCKS_PER_B 128   // 128 blocks/batch, 4 waves, wave-private 64x64 tiles

// workspace layout (floats), "full" path (partials, no atomics)
static const size_t OFF_PART = 0;                               // [256][4096]
static const size_t OFF_G    = (size_t)256 * 4096;              // [4][4096]
static const size_t OFF_T1   = OFF_G  + (size_t)BATCH * 4096;   // [4][64][64]
static const size_t OFF_INV  = OFF_T1 + (size_t)BATCH * 4096;   // [4][128]
static const size_t OFF_MT   = OFF_INV + (size_t)BATCH * 128;   // [4][64][64] (M transposed: [c][d])
static const size_t WS_FLOATS_FULL = OFF_MT + (size_t)BATCH * 4096;

// small-ws fallback (atomic G accumulation)
static const size_t SOFF_G   = 0;
static const size_t SOFF_T1  = (size_t)BATCH * 4096;
static const size_t SOFF_INV = SOFF_T1 + (size_t)BATCH * 4096;
static const size_t SOFF_MT  = SOFF_INV + (size_t)BATCH * 128;

__global__ void k_zero(float* __restrict__ p, int n) {
  int i = blockIdx.x * blockDim.x + threadIdx.x;
  if (i < n) p[i] = 0.f;
}

// ---------------------------------------------------------------------------
// G = X X^T. 8 waves/block; each wave owns a 200-token stripe; lane (li,lj)
// accumulates the 8x8 sub-tile (c1=8li+u, c2=8lj+v) in registers; A and B both
// come straight from global (L1 merges the 8-lane duplication). 8-token steps
// keep 32 dwordx4 loads in flight per wave for HBM latency hiding.
// ---------------------------------------------------------------------------
template <bool ATOMIC>
__global__ __launch_bounds__(512, 2) void k_gram(const float* __restrict__ x,
                                                 float* __restrict__ dstG) {
  __shared__ float red[4][64][64];  // 64 KB cross-wave reduction buffer
  const int b = blockIdx.y;
  const int blk = blockIdx.x;
  const int tid = threadIdx.x;
  const int w = tid >> 6;
  const int lane = tid & 63;
  const int li = lane >> 3;
  const int lj = lane & 7;

  const float* xb = x + (size_t)b * CH * NTOK;
  const int base = blk * 1600 + w * 200;

  float acc[8][8];
#pragma unroll
  for (int u = 0; u < 8; ++u)
#pragma unroll
    for (int v = 0; v < 8; ++v) acc[u][v] = 0.f;

#pragma unroll 1
  for (int s = 0; s < 25; ++s) {
    const int t = base + s * 8;
    float4 A[8][2], Bv[8][2];
#pragma unroll
    for (int u = 0; u < 8; ++u) {
      const float* pa = xb + (size_t)(8 * li + u) * NTOK + t;
      A[u][0] = *(const float4*)pa;
      A[u][1] = *(const float4*)(pa + 4);
      const float* pb = xb + (size_t)(8 * lj + u) * NTOK + t;
      Bv[u][0] = *(const float4*)pb;
      Bv[u][1] = *(const float4*)(pb + 4);
    }
#pragma unroll
    for (int u = 0; u < 8; ++u) {
#pragma unroll
      for (int v = 0; v < 8; ++v) {
        float a = acc[u][v];
        a = fmaf(A[u][0].x, Bv[v][0].x, a);
        a = fmaf(A[u][0].y, Bv[v][0].y, a);
        a = fmaf(A[u][0].z, Bv[v][0].z, a);
        a = fmaf(A[u][0].w, Bv[v][0].w, a);
        a = fmaf(A[u][1].x, Bv[v][1].x, a);
        a = fmaf(A[u][1].y, Bv[v][1].y, a);
        a = fmaf(A[u][1].z, Bv[v][1].z, a);
        a = fmaf(A[u][1].w, Bv[v][1].w, a);
        acc[u][v] = a;
      }
    }
  }

  // cross-wave reduce: waves 4..7 store, waves 0..3 add into same buffers
  if (w >= 4) {
#pragma unroll
    for (int u = 0; u < 8; ++u) {
      *(float4*)&red[w - 4][8 * li + u][8 * lj] =
          make_float4(acc[u][0], acc[u][1], acc[u][2], acc[u][3]);
      *(float4*)&red[w - 4][8 * li + u][8 * lj + 4] =
          make_float4(acc[u][4], acc[u][5], acc[u][6], acc[u][7]);
    }
  }
  __syncthreads();
  if (w < 4) {
#pragma unroll
    for (int u = 0; u < 8; ++u) {
      float4* p0 = (float4*)&red[w][8 * li + u][8 * lj];
      float4* p1 = (float4*)&red[w][8 * li + u][8 * lj + 4];
      float4 r0 = *p0, r1 = *p1;
      r0.x += acc[u][0]; r0.y += acc[u][1]; r0.z += acc[u][2]; r0.w += acc[u][3];
      r1.x += acc[u][4]; r1.y += acc[u][5]; r1.z += acc[u][6]; r1.w += acc[u][7];
      *p0 = r0; *p1 = r1;
    }
  }
  __syncthreads();

  const float* rf = &red[0][0][0];
  const int e8 = tid * 8;
  float o[8];
#pragma unroll
  for (int k = 0; k < 8; ++k) o[k] = 0.f;
#pragma unroll
  for (int p = 0; p < 4; ++p) {
    const float4* rp = (const float4*)(rf + p * 4096 + e8);
    float4 a0 = rp[0], a1 = rp[1];
    o[0] += a0.x; o[1] += a0.y; o[2] += a0.z; o[3] += a0.w;
    o[4] += a1.x; o[5] += a1.y; o[6] += a1.z; o[7] += a1.w;
  }
  if (ATOMIC) {
    float* g = dstG + (size_t)b * 4096 + e8;
#pragma unroll
    for (int k = 0; k < 8; ++k) atomicAdd(g + k, o[k]);
  } else {
    float* dst = dstG + ((size_t)(b * GRAM_BLOCKS_PER_B + blk)) * 4096 + e8;
    *(float4*)dst = make_float4(o[0], o[1], o[2], o[3]);
    *(float4*)(dst + 4) = make_float4(o[4], o[5], o[6], o[7]);
  }
}

// G[b][e] = sum over 64 per-block partials (deterministic, coalesced)
__global__ void k_reduceG(const float* __restrict__ partG, float* __restrict__ G) {
  const int el = blockIdx.x * 256 + threadIdx.x;  // 0..16383
  const int b = el >> 12;
  const int e = el & 4095;
  const float* p = partG + (size_t)b * GRAM_BLOCKS_PER_B * 4096 + e;
  float s = 0.f;
#pragma unroll
  for (int q = 0; q < GRAM_BLOCKS_PER_B; ++q) s += p[(size_t)q * 4096];
  G[el] = s;
}

// ---------------------------------------------------------------------------
// One wave per (batch, row r in 0..127): T_row = W[r] @ G ; norm^2 = T_row.W[r]
// Store T1 (q rows only) pre-scaled by 1/max(norm, eps); store inv for all rows.
// ---------------------------------------------------------------------------
__global__ void k_rows(const float* __restrict__ W, const float* __restrict__ G,
                       float* __restrict__ T1, float* __restrict__ inv) {
  const int r = blockIdx.x;  // 0..127 (q rows then k rows)
  const int b = blockIdx.y;
  const int lane = threadIdx.x;  // 64
  const float* Wr = W + r * 64;
  const float* Gb = G + (size_t)b * 4096;
  float acc = 0.f;
#pragma unroll 8
  for (int c = 0; c < 64; ++c) acc = fmaf(Wr[c], Gb[c * 64 + lane], acc);
  float p = acc * Wr[lane];
#pragma unroll
  for (int m = 1; m < 64; m <<= 1) p += __shfl_xor(p, m, 64);
  const float nrm = sqrtf(fmaxf(p, 0.f));
  const float iv = 1.f / fmaxf(nrm, 1e-12f);
  if (r < 64) T1[((size_t)b * 64 + r) * 64 + lane] = acc * iv;
  if (lane == 0) inv[b * 128 + r] = iv;
}

// ---------------------------------------------------------------------------
// Per (batch, 16-row quadrant): att = softmax(T1 Wk^T * inv_k); MT[c][d] = (att Wv)^T
// ---------------------------------------------------------------------------
__global__ void k_att(const float* __restrict__ W, const float* __restrict__ T1,
                      const float* __restrict__ inv, float* __restrict__ MT) {
  __shared__ float WkT[64][65];   // [c][e], conflict-free scalar reads
  __shared__ float T1s[16][64];   // broadcast reads
  __shared__ float att[16][64];
  const int b = blockIdx.y;
  const int d0 = blockIdx.x * 16;
  const int tid = threadIdx.x;
  const int w = tid >> 6;
  const int lane = tid & 63;

#pragma unroll
  for (int r = 0; r < 16; ++r) {
    const int e = w + 4 * r;  // 0..63
    WkT[lane][e] = W[(64 + e) * 64 + lane];
  }
#pragma unroll
  for (int r = 0; r < 4; ++r) {
    const int dd = w + 4 * r;  // 0..15
    T1s[dd][lane] = T1[((size_t)b * 64 + d0 + dd) * 64 + lane];
  }
  __syncthreads();

  const float invk = inv[b * 128 + 64 + lane];
  float a[4];
#pragma unroll
  for (int it = 0; it < 4; ++it) {
    const int dd = 4 * w + it;
    float s = 0.f;
#pragma unroll 8
    for (int c = 0; c < 64; ++c) s = fmaf(T1s[dd][c], WkT[c][lane], s);
    a[it] = s * invk;
  }
  // softmax over e (lanes) per row
#pragma unroll
  for (int it = 0; it < 4; ++it) {
    float m = a[it];
#pragma unroll
    for (int k = 1; k < 64; k <<= 1) m = fmaxf(m, __shfl_xor(m, k, 64));
    const float e = expf(a[it] - m);
    float s = e;
#pragma unroll
    for (int k = 1; k < 64; k <<= 1) s += __shfl_xor(s, k, 64);
    att[4 * w + it][lane] = e / s;
  }
  __syncthreads();
  // M[d][c] = sum_e att[d][e] * Wv[e][c]; lane = c; store transposed MT[c][d]
#pragma unroll
  for (int it = 0; it < 4; ++it) {
    const int dd = 4 * w + it;
    float m = 0.f;
#pragma unroll 8
    for (int e = 0; e < 64; ++e) m = fmaf(att[dd][e], W[(128 + e) * 64 + lane], m);
    MT[(size_t)b * 4096 + lane * 64 + (d0 + dd)] = m;
  }
}

// ---------------------------------------------------------------------------
// out[d][t] = sum_c MT[c][d] * x[c][t]. Wave-private 64x64 LDS x-tile (no
// barrier in the loop); A (MT, 16 KB) streamed from global -> L1-hot; 8x8
// per-lane register tile; c is wave-uniform so LDS reads are 2-way (free).
// ---------------------------------------------------------------------------
__global__ __launch_bounds__(256) void k_out(const float* __restrict__ x,
                                             const float* __restrict__ MT,
                                             float* __restrict__ out) {
  __shared__ float xt[4][64][64];  // 64 KB, one [64][64] tile per wave
  const int b = blockIdx.y;
  const int blk = blockIdx.x;  // 0..127
  const int tid = threadIdx.x;
  const int w = tid >> 6;
  const int lane = tid & 63;
  const int li = lane >> 3;
  const int lj = lane & 7;

  const float* xb = x + (size_t)b * CH * NTOK;
  const float4* mt4 = (const float4*)(MT + (size_t)b * 4096);
  float* ob = out + (size_t)b * DIM * NTOK;
  float* xl = &xt[w][0][0];

  const int wv = blk * 4 + w;  // 0..511 per batch
  const int rr = lane >> 4;
  const int tt4 = (lane & 15) * 4;

#pragma unroll 1
  for (int tl = wv; tl < 1600; tl += 512) {
    const int t0 = tl * 64;
    // stage x tile [c][t] (coalesced float4 loads, b128 LDS writes)
#pragma unroll
    for (int g = 0; g < 16; ++g) {
      const int c = 4 * g + rr;
      const float4 v = *(const float4*)(xb + (size_t)c * NTOK + t0 + tt4);
      *(float4*)&xl[c * 64 + tt4] = v;
    }

    float acc[8][8];
#pragma unroll
    for (int u = 0; u < 8; ++u)
#pragma unroll
      for (int v = 0; v < 8; ++v) acc[u][v] = 0.f;

#pragma unroll 4
    for (int c = 0; c < 64; ++c) {
      const float4 a0 = mt4[c * 16 + 2 * li];
      const float4 a1 = mt4[c * 16 + 2 * li + 1];
      const float4 b0 = *(const float4*)&xl[c * 64 + 8 * lj];
      const float4 b1 = *(const float4*)&xl[c * 64 + 8 * lj + 4];
      const float av[8] = {a0.x, a0.y, a0.z, a0.w, a1.x, a1.y, a1.z, a1.w};
      const float bw[8] = {b0.x, b0.y, b0.z, b0.w, b1.x, b1.y, b1.z, b1.w};
#pragma unroll
      for (int u = 0; u < 8; ++u)
#pragma unroll
        for (int v = 0; v < 8; ++v) acc[u][v] = fmaf(av[u], bw[v], acc[u][v]);
    }

#pragma unroll
    for (int u = 0; u < 8; ++u) {
      float* dst = ob + (size_t)(8 * li + u) * NTOK + t0 + 8 * lj;
      *(float4*)dst = make_float4(acc[u][0], acc[u][1], acc[u][2], acc[u][3]);
      *(float4*)(dst + 4) = make_float4(acc[u][4], acc[u][5], acc[u][6], acc[u][7]);
    }
  }
}

extern "C" void kernel_launch(void* const* d_in, const int* in_sizes, int n_in,
                              void* d_out, int out_size, void* d_ws, size_t ws_size,
                              hipStream_t stream) {
  const float* x = (const float*)d_in[0];
  const float* W = (const float*)d_in[1];
  float* out = (float*)d_out;
  float* ws = (float*)d_ws;

  if (ws_size >= WS_FLOATS_FULL * sizeof(float)) {
    float* partG = ws + OFF_PART;
    float* G = ws + OFF_G;
    float* T1 = ws + OFF_T1;
    float* inv = ws + OFF_INV;
    float* MT = ws + OFF_MT;
    k_gram<false><<<dim3(GRAM_BLOCKS_PER_B, BATCH), 512, 0, stream>>>(x, partG);
    k_reduceG<<<dim3(64), 256, 0, stream>>>(partG, G);
    k_rows<<<dim3(128, BATCH), 64, 0, stream>>>(W, G, T1, inv);
    k_att<<<dim3(4, BATCH), 256, 0, stream>>>(W, T1, inv, MT);
    k_out<<<dim3(OUT_BLOCKS_PER_B, BATCH), 256, 0, stream>>>(x, MT, out);
  } else {
    float* G = ws + SOFF_G;
    float* T1 = ws + SOFF_T1;
    float* inv = ws + SOFF_INV;
    float* MT = ws + SOFF_MT;
    k_zero<<<dim3(64), 256, 0, stream>>>(G, BATCH * 4096);
    k_gram<true><<<dim3(GRAM_BLOCKS_PER_B, BATCH), 512, 0, stream>>>(x, G);
    k_rows<<<dim3(128, BATCH), 64, 0, stream>>>(W, G, T1, inv);
    k_att<<<dim3(4, BATCH), 256, 0, stream>>>(W, T1, inv, MT);
    k_out<<<dim3(OUT_BLOCKS_PER_B, BATCH), 256, 0, stream>>>(x, MT, out);
  }
}

// Round 3
// 335.675 us; speedup vs baseline: 1.0817x; 1.0817x over previous
//
#include <hip/hip_runtime.h>
#include <hip/hip_bf16.h>

// FrequencyAttention:
//   G = X X^T (per batch, 64x64)            -> k_gram (+ k_reduceG)
//   T1 = inv_q * (Wq G); norms via diag     -> k_rows
//   att = softmax(T1 Wk^T * inv_k); M=att Wv-> k_att
//   out = M X                               -> k_out
// B=4, C=64, N=102400, D=64. W rows: [0:64]=Wq, [64:128]=Wk, [128:192]=Wv.
//
// Structure: async global_load_lds double-buffered [64][64] f32 tiles,
// XOR-swizzled (on the GLOBAL source; LDS dest must stay linear), 256-thread
// blocks, 16-acc lane tiles, 5 blocks/CU.

#define BATCH 4
#define CH 64
#define NTOK 102400
#define DIM 64

#define GBLK 320            // blocks per batch; 5 tiles of 64 tokens each
#define TILES_PER_BLK 5

// workspace layout (floats), full path
static const size_t OFF_PART = 0;                                    // [4*320][4096]
static const size_t OFF_G    = (size_t)BATCH * GBLK * 4096;          // [4][4096]
static const size_t OFF_T1   = OFF_G  + (size_t)BATCH * 4096;        // [4][64][64]
static const size_t OFF_INV  = OFF_T1 + (size_t)BATCH * 4096;        // [4][128]
static const size_t OFF_MT   = OFF_INV + (size_t)BATCH * 128;        // [4][64][64] ([c][d])
static const size_t WS_FLOATS_FULL = OFF_MT + (size_t)BATCH * 4096;

// small-ws fallback (atomic G accumulation)
static const size_t SOFF_G   = 0;
static const size_t SOFF_T1  = (size_t)BATCH * 4096;
static const size_t SOFF_INV = SOFF_T1 + (size_t)BATCH * 4096;
static const size_t SOFF_MT  = SOFF_INV + (size_t)BATCH * 128;

__global__ void k_zero(float* __restrict__ p, int n) {
  int i = blockIdx.x * blockDim.x + threadIdx.x;
  if (i < n) p[i] = 0.f;
}

// ---------------------------------------------------------------------------
// Tile staging: [64][64] f32 tile (16 KB), 16 chunks of 1 KB (4 rows each).
// global_load_lds writes LDS linearly (base + lane*16B); the bank-conflict
// swizzle is applied by permuting the GLOBAL source granule: LDS slot g of
// row r holds global granule g ^ ((r>>2)&7) (involution). ds_read side uses
// the same XOR. Result: any instr reading 8 rows {4a+u : a=0..7} at one
// token-granule hits 8 distinct bank-quads -> conflict-free.
// ---------------------------------------------------------------------------
__device__ __forceinline__ void stage_tile64(const float* __restrict__ xrow0,
                                             float* tile, int w, int lane) {
#pragma unroll
  for (int k = 0; k < 4; ++k) {
    const int chunk = w * 4 + k;
    const int r = chunk * 4 + (lane >> 4);
    const int gp = lane & 15;
    const int gs = gp ^ ((r >> 2) & 7);
    const float* g = xrow0 + (size_t)r * NTOK + 4 * gs;
    float* l = tile + chunk * 256;  // 1 KB chunk, lane offset added by HW
    __builtin_amdgcn_global_load_lds((const __attribute__((address_space(1))) void*)g,
                                     (__attribute__((address_space(3))) void*)l,
                                     16, 0, 0);
  }
}

__device__ __forceinline__ float4 rd_tile(const float* tile, int r, int g) {
  return *(const float4*)(tile + r * 64 + 4 * (g ^ ((r >> 2) & 7)));
}

#define VM_WAIT0() do { \
    asm volatile("s_waitcnt vmcnt(0)" ::: "memory"); \
    __builtin_amdgcn_sched_barrier(0); \
    __builtin_amdgcn_s_barrier(); \
  } while (0)

// ---------------------------------------------------------------------------
// k_gram: block = 4 waves; wave (qi,qj) computes a 32x32 quadrant of the
// 64x64 G partial over the block's 320 tokens. Lane (a=lane>>3, b=lane&7)
// holds a 4x4 acc. Quadrants are disjoint -> no cross-wave reduction.
// ---------------------------------------------------------------------------
template <bool ATOMIC>
__global__ __launch_bounds__(256, 5) void k_gram(const float* __restrict__ x,
                                                 float* __restrict__ dstG) {
  __shared__ float tiles[2][4096];
  const int b = blockIdx.y;
  const int blk = blockIdx.x;
  const int tid = threadIdx.x;
  const int w = tid >> 6;
  const int lane = tid & 63;
  const int qi = w >> 1, qj = w & 1;
  const int a = lane >> 3, bb = lane & 7;

  const float* xb = x + (size_t)b * CH * NTOK;
  const int t0 = blk * (TILES_PER_BLK * 64);

  float acc[4][4] = {};

  stage_tile64(xb + t0, tiles[0], w, lane);
  VM_WAIT0();

#pragma unroll 1
  for (int i = 0; i < TILES_PER_BLK; ++i) {
    if (i + 1 < TILES_PER_BLK)
      stage_tile64(xb + t0 + 64 * (i + 1), tiles[(i + 1) & 1], w, lane);
    const float* tb = tiles[i & 1];
#pragma unroll
    for (int gt = 0; gt < 16; ++gt) {
      float4 Av[4], Bv[4];
#pragma unroll
      for (int u = 0; u < 4; ++u) Av[u] = rd_tile(tb, 32 * qi + 4 * a + u, gt);
#pragma unroll
      for (int v = 0; v < 4; ++v) Bv[v] = rd_tile(tb, 32 * qj + 4 * bb + v, gt);
#pragma unroll
      for (int u = 0; u < 4; ++u)
#pragma unroll
        for (int v = 0; v < 4; ++v) {
          float s = acc[u][v];
          s = fmaf(Av[u].x, Bv[v].x, s);
          s = fmaf(Av[u].y, Bv[v].y, s);
          s = fmaf(Av[u].z, Bv[v].z, s);
          s = fmaf(Av[u].w, Bv[v].w, s);
          acc[u][v] = s;
        }
    }
    VM_WAIT0();
  }

  if (ATOMIC) {
    float* g = dstG + (size_t)b * 4096;
#pragma unroll
    for (int u = 0; u < 4; ++u)
#pragma unroll
      for (int v = 0; v < 4; ++v)
        atomicAdd(g + (32 * qi + 4 * a + u) * 64 + 32 * qj + 4 * bb + v, acc[u][v]);
  } else {
    float* dst = dstG + ((size_t)(b * GBLK + blk)) * 4096;
#pragma unroll
    for (int u = 0; u < 4; ++u) {
      *(float4*)(dst + (32 * qi + 4 * a + u) * 64 + 32 * qj + 4 * bb) =
          make_float4(acc[u][0], acc[u][1], acc[u][2], acc[u][3]);
    }
  }
}

// G[b][e] = sum over 320 per-block partials (coalesced across lanes)
__global__ void k_reduceG(const float* __restrict__ partG, float* __restrict__ G) {
  const int el = blockIdx.x * 256 + threadIdx.x;  // 0..16383
  const int b = el >> 12;
  const int e = el & 4095;
  const float* p = partG + (size_t)b * GBLK * 4096 + e;
  float s = 0.f;
#pragma unroll 8
  for (int q = 0; q < GBLK; ++q) s += p[(size_t)q * 4096];
  G[el] = s;
}

// ---------------------------------------------------------------------------
// One wave per (batch, row r in 0..127): T_row = W[r] @ G ; norm^2 = T_row.W[r]
// ---------------------------------------------------------------------------
__global__ void k_rows(const float* __restrict__ W, const float* __restrict__ G,
                       float* __restrict__ T1, float* __restrict__ inv) {
  const int r = blockIdx.x;  // 0..127 (q rows then k rows)
  const int b = blockIdx.y;
  const int lane = threadIdx.x;  // 64
  const float* Wr = W + r * 64;
  const float* Gb = G + (size_t)b * 4096;
  float acc = 0.f;
#pragma unroll 8
  for (int c = 0; c < 64; ++c) acc = fmaf(Wr[c], Gb[c * 64 + lane], acc);
  float p = acc * Wr[lane];
#pragma unroll
  for (int m = 1; m < 64; m <<= 1) p += __shfl_xor(p, m, 64);
  const float nrm = sqrtf(fmaxf(p, 0.f));
  const float iv = 1.f / fmaxf(nrm, 1e-12f);
  if (r < 64) T1[((size_t)b * 64 + r) * 64 + lane] = acc * iv;
  if (lane == 0) inv[b * 128 + r] = iv;
}

// ---------------------------------------------------------------------------
// Per (batch, 16-row quadrant): att = softmax(T1 Wk^T * inv_k); MT[c][d]=(att Wv)^T
// ---------------------------------------------------------------------------
__global__ void k_att(const float* __restrict__ W, const float* __restrict__ T1,
                      const float* __restrict__ inv, float* __restrict__ MT) {
  __shared__ float WkT[64][65];
  __shared__ float T1s[16][64];
  __shared__ float att[16][64];
  const int b = blockIdx.y;
  const int d0 = blockIdx.x * 16;
  const int tid = threadIdx.x;
  const int w = tid >> 6;
  const int lane = tid & 63;

#pragma unroll
  for (int r = 0; r < 16; ++r) {
    const int e = w + 4 * r;
    WkT[lane][e] = W[(64 + e) * 64 + lane];
  }
#pragma unroll
  for (int r = 0; r < 4; ++r) {
    const int dd = w + 4 * r;
    T1s[dd][lane] = T1[((size_t)b * 64 + d0 + dd) * 64 + lane];
  }
  __syncthreads();

  const float invk = inv[b * 128 + 64 + lane];
  float a[4];
#pragma unroll
  for (int it = 0; it < 4; ++it) {
    const int dd = 4 * w + it;
    float s = 0.f;
#pragma unroll 8
    for (int c = 0; c < 64; ++c) s = fmaf(T1s[dd][c], WkT[c][lane], s);
    a[it] = s * invk;
  }
#pragma unroll
  for (int it = 0; it < 4; ++it) {
    float m = a[it];
#pragma unroll
    for (int k = 1; k < 64; k <<= 1) m = fmaxf(m, __shfl_xor(m, k, 64));
    const float e = expf(a[it] - m);
    float s = e;
#pragma unroll
    for (int k = 1; k < 64; k <<= 1) s += __shfl_xor(s, k, 64);
    att[4 * w + it][lane] = e / s;
  }
  __syncthreads();
#pragma unroll
  for (int it = 0; it < 4; ++it) {
    const int dd = 4 * w + it;
    float m = 0.f;
#pragma unroll 8
    for (int e = 0; e < 64; ++e) m = fmaf(att[dd][e], W[(128 + e) * 64 + lane], m);
    MT[(size_t)b * 4096 + lane * 64 + (d0 + dd)] = m;
  }
}

// ---------------------------------------------------------------------------
// k_out: out[d][t] = sum_c MT[c][d] * x[c][t]. Same staged-tile structure.
// Wave w owns rows 16w..16w+15 x 64 tokens; lane (a2=lane>>4, b2=lane&15)
// holds 4x4 acc (rows 16w+4a2+u, tokens 4b2+v). A (MT slice) from global,
// L1-hot; B from swizzled LDS tile.
// ---------------------------------------------------------------------------
__global__ __launch_bounds__(256, 5) void k_out(const float* __restrict__ x,
                                                const float* __restrict__ MT,
                                                float* __restrict__ out) {
  __shared__ float tiles[2][4096];
  const int b = blockIdx.y;
  const int blk = blockIdx.x;
  const int tid = threadIdx.x;
  const int w = tid >> 6;
  const int lane = tid & 63;
  const int a2 = lane >> 4, b2 = lane & 15;

  const float* xb = x + (size_t)b * CH * NTOK;
  const float* MTb = MT + (size_t)b * 4096;
  float* ob = out + (size_t)b * DIM * NTOK;
  const int t0 = blk * (TILES_PER_BLK * 64);
  const int row0 = 16 * w + 4 * a2;

  stage_tile64(xb + t0, tiles[0], w, lane);
  VM_WAIT0();

#pragma unroll 1
  for (int i = 0; i < TILES_PER_BLK; ++i) {
    if (i + 1 < TILES_PER_BLK)
      stage_tile64(xb + t0 + 64 * (i + 1), tiles[(i + 1) & 1], w, lane);
    const float* tb = tiles[i & 1];

    float acc[4][4] = {};
#pragma unroll 4
    for (int c = 0; c < 64; ++c) {
      const float4 Am = *(const float4*)(MTb + c * 64 + row0);
      const float4 Bx = rd_tile(tb, c, b2);
      const float am[4] = {Am.x, Am.y, Am.z, Am.w};
      const float bx[4] = {Bx.x, Bx.y, Bx.z, Bx.w};
#pragma unroll
      for (int u = 0; u < 4; ++u)
#pragma unroll
        for (int v = 0; v < 4; ++v) acc[u][v] = fmaf(am[u], bx[v], acc[u][v]);
    }

    const int tt = t0 + 64 * i + 4 * b2;
#pragma unroll
    for (int u = 0; u < 4; ++u) {
      *(float4*)(ob + (size_t)(row0 + u) * NTOK + tt) =
          make_float4(acc[u][0], acc[u][1], acc[u][2], acc[u][3]);
    }
    VM_WAIT0();
  }
}

extern "C" void kernel_launch(void* const* d_in, const int* in_sizes, int n_in,
                              void* d_out, int out_size, void* d_ws, size_t ws_size,
                              hipStream_t stream) {
  const float* x = (const float*)d_in[0];
  const float* W = (const float*)d_in[1];
  float* out = (float*)d_out;
  float* ws = (float*)d_ws;

  if (ws_size >= WS_FLOATS_FULL * sizeof(float)) {
    float* partG = ws + OFF_PART;
    float* G = ws + OFF_G;
    float* T1 = ws + OFF_T1;
    float* inv = ws + OFF_INV;
    float* MT = ws + OFF_MT;
    k_gram<false><<<dim3(GBLK, BATCH), 256, 0, stream>>>(x, partG);
    k_reduceG<<<dim3(64), 256, 0, stream>>>(partG, G);
    k_rows<<<dim3(128, BATCH), 64, 0, stream>>>(W, G, T1, inv);
    k_att<<<dim3(4, BATCH), 256, 0, stream>>>(W, T1, inv, MT);
    k_out<<<dim3(GBLK, BATCH), 256, 0, stream>>>(x, MT, out);
  } else {
    float* G = ws + SOFF_G;
    float* T1 = ws + SOFF_T1;
    float* inv = ws + SOFF_INV;
    float* MT = ws + SOFF_MT;
    k_zero<<<dim3(64), 256, 0, stream>>>(G, BATCH * 4096);
    k_gram<true><<<dim3(GBLK, BATCH), 256, 0, stream>>>(x, G);
    k_rows<<<dim3(128, BATCH), 64, 0, stream>>>(W, G, T1, inv);
    k_att<<<dim3(4, BATCH), 256, 0, stream>>>(W, T1, inv, MT);
    k_out<<<dim3(GBLK, BATCH), 256, 0, stream>>>(x, MT, out);
  }
}

// Round 6
// 284.845 us; speedup vs baseline: 1.2748x; 1.1785x over previous
//
#include <hip/hip_runtime.h>
#include <hip/hip_bf16.h>

// FrequencyAttention:
//   G = X X^T (per batch, 64x64)            -> k_gram (MFMA bf16 hi/lo split) + k_reduceG
//   T1 = inv_q * (Wq G); norms via diag     -> k_rows
//   att = softmax(T1 Wk^T * inv_k); M=att Wv-> k_att
//   out = M X                               -> k_out (fp32 VALU, broadcast-LDS B, L1 A)
// B=4, C=64, N=102400, D=64. W rows: [0:64]=Wq, [64:128]=Wk, [128:192]=Wv.
//
// G via MFMA: x = hi + lo (bf16 RNE split). G = hi hi^T + P2 + P2^T, P2 = hi lo^T
// (lo lo^T dropped, ~1e-3 absolute vs sigma=320 entries). P2^T folded in-block via
// padded-LDS transpose, so per-block partial stays one 64x64 matrix.

#define BATCH 4
#define CH 64
#define NTOK 102400
#define DIM 64

#define NBLK_G 200          // gram blocks per batch
#define TOK_PER_G 512       // tokens per gram block = 8 tiles of 64
#define GBLK_OUT 320        // out blocks per batch
#define TILES_PER_BLK 5     // 64-token tiles per out block

// workspace layout (floats)
static const size_t OFF_PART = 0;                                    // [4*200][4096]
static const size_t OFF_G    = (size_t)BATCH * NBLK_G * 4096;        // [4][4096]
static const size_t OFF_T1   = OFF_G  + (size_t)BATCH * 4096;        // [4][64][64]
static const size_t OFF_INV  = OFF_T1 + (size_t)BATCH * 4096;        // [4][128]
static const size_t OFF_MT   = OFF_INV + (size_t)BATCH * 128;        // [4][64][64] ([c][d])
static const size_t WS_FLOATS_FULL = OFF_MT + (size_t)BATCH * 4096;

// small-ws fallback (atomic G accumulation)
static const size_t SOFF_G   = 0;
static const size_t SOFF_T1  = (size_t)BATCH * 4096;
static const size_t SOFF_INV = SOFF_T1 + (size_t)BATCH * 4096;
static const size_t SOFF_MT  = SOFF_INV + (size_t)BATCH * 128;

typedef __attribute__((ext_vector_type(8))) short short8v;
typedef __attribute__((ext_vector_type(4))) float f32x4;

__global__ void k_zero(float* __restrict__ p, int n) {
  int i = blockIdx.x * blockDim.x + threadIdx.x;
  if (i < n) p[i] = 0.f;
}

__device__ __forceinline__ short f2bf(float f) {  // RNE fp32->bf16 bits
  unsigned u = __builtin_bit_cast(unsigned, f);
  unsigned r = (u + 0x7fffu + ((u >> 16) & 1u)) >> 16;
  return (short)r;
}
__device__ __forceinline__ float bf2f(short s) {
  unsigned u = ((unsigned)(unsigned short)s) << 16;
  return __builtin_bit_cast(float, u);
}

// ---------------------------------------------------------------------------
// k_gram: 256 thr / 4 waves. Tile = [64 ch][64 tok] as hi/lo bf16 in LDS,
// double-buffered, granule(16B=8tok)-XOR swizzled: slot = g ^ (row&7).
// Staging: thread (cs=tid>>2, tq=tid&3) loads 16 fp32 tokens of channel cs,
// converts to hi/lo, writes 2+2 b128 (conflict-free: 64 distinct 16B addrs).
// Compute: wave w = A-rowblock (channels 16w..16w+15); per K=32 chunk kc:
//   A-frag: lane -> row 16w+(l&15), tokens 8*(l>>4)+j  (guide-verified layout)
//   B-frags: 4 colblocks, hi and lo -> 16x16x32 MFMA, acc1 (hi hi) acc2 (hi lo)
// Epilogue: P2^T via padded LDS transpose; store P1+P2+P2^T partial per block.
// ---------------------------------------------------------------------------
template <bool ATOMIC>
__global__ __launch_bounds__(256, 3) void k_gram(const float* __restrict__ x,
                                                 float* __restrict__ dstG) {
  __shared__ short his[2][4096];
  __shared__ short los[2][4096];
  __shared__ float p2t[64][65];
  const int b = blockIdx.y, blk = blockIdx.x;
  const int tid = threadIdx.x;
  const int w = tid >> 6, lane = tid & 63;
  const int col = lane & 15, kh = lane >> 4;   // frag column / k-half
  const int cs = tid >> 2, tq = tid & 3;       // staging: channel, token-quarter

  const float* xb = x + (size_t)b * CH * NTOK;
  const int t0 = blk * TOK_PER_G;

  f32x4 a1[4], a2[4];
#pragma unroll
  for (int cb = 0; cb < 4; ++cb)
#pragma unroll
    for (int r = 0; r < 4; ++r) { a1[cb][r] = 0.f; a2[cb][r] = 0.f; }

  const int sbase = cs * 64;
  const int s0 = ((2 * tq) ^ (cs & 7)) << 3;
  const int s1 = ((2 * tq + 1) ^ (cs & 7)) << 3;

  // prologue: stage tile 0
  {
    const float* src = xb + (size_t)cs * NTOK + t0 + 16 * tq;
    float4 v0 = *(const float4*)(src);
    float4 v1 = *(const float4*)(src + 4);
    float4 v2 = *(const float4*)(src + 8);
    float4 v3 = *(const float4*)(src + 12);
    float f[16] = {v0.x, v0.y, v0.z, v0.w, v1.x, v1.y, v1.z, v1.w,
                   v2.x, v2.y, v2.z, v2.w, v3.x, v3.y, v3.z, v3.w};
    short8v h01, h23, l01, l23;
#pragma unroll
    for (int j = 0; j < 8; ++j) {
      short h = f2bf(f[j]);     h01[j] = h; l01[j] = f2bf(f[j] - bf2f(h));
      short g = f2bf(f[j + 8]); h23[j] = g; l23[j] = f2bf(f[j + 8] - bf2f(g));
    }
    *(short8v*)&his[0][sbase + s0] = h01;
    *(short8v*)&his[0][sbase + s1] = h23;
    *(short8v*)&los[0][sbase + s0] = l01;
    *(short8v*)&los[0][sbase + s1] = l23;
  }
  __syncthreads();

#pragma unroll 1
  for (int i = 0; i < TOK_PER_G / 64; ++i) {
    const int cur = i & 1;
    const bool more = (i + 1) < TOK_PER_G / 64;
    float4 n0, n1, n2, n3;
    if (more) {  // issue next-tile global loads early (latency hides under MFMA)
      const float* src = xb + (size_t)cs * NTOK + t0 + (i + 1) * 64 + 16 * tq;
      n0 = *(const float4*)(src);
      n1 = *(const float4*)(src + 4);
      n2 = *(const float4*)(src + 8);
      n3 = *(const float4*)(src + 12);
    }
    const short* hp = his[cur];
    const short* lp = los[cur];
#pragma unroll
    for (int kc = 0; kc < 2; ++kc) {
      const int g = kc * 4 + kh;
      const int rA = 16 * w + col;
      const short8v A = *(const short8v*)&hp[rA * 64 + ((g ^ (rA & 7)) << 3)];
#pragma unroll
      for (int cb = 0; cb < 4; ++cb) {
        const int rB = 16 * cb + col;
        const int off = rB * 64 + ((g ^ (rB & 7)) << 3);
        const short8v Bh = *(const short8v*)&hp[off];
        const short8v Bl = *(const short8v*)&lp[off];
        a1[cb] = __builtin_amdgcn_mfma_f32_16x16x32_bf16(A, Bh, a1[cb], 0, 0, 0);
        a2[cb] = __builtin_amdgcn_mfma_f32_16x16x32_bf16(A, Bl, a2[cb], 0, 0, 0);
      }
    }
    if (more) {
      const int nxt = cur ^ 1;
      float f[16] = {n0.x, n0.y, n0.z, n0.w, n1.x, n1.y, n1.z, n1.w,
                     n2.x, n2.y, n2.z, n2.w, n3.x, n3.y, n3.z, n3.w};
      short8v h01, h23, l01, l23;
#pragma unroll
      for (int j = 0; j < 8; ++j) {
        short h = f2bf(f[j]);     h01[j] = h; l01[j] = f2bf(f[j] - bf2f(h));
        short g2 = f2bf(f[j + 8]); h23[j] = g2; l23[j] = f2bf(f[j + 8] - bf2f(g2));
      }
      *(short8v*)&his[nxt][sbase + s0] = h01;
      *(short8v*)&his[nxt][sbase + s1] = h23;
      *(short8v*)&los[nxt][sbase + s0] = l01;
      *(short8v*)&los[nxt][sbase + s1] = l23;
    }
    __syncthreads();
  }

  // epilogue: fold P2^T. C/D layout (verified m89/m91): col=lane&15, row=(lane>>4)*4+reg.
#pragma unroll
  for (int cb = 0; cb < 4; ++cb)
#pragma unroll
    for (int r = 0; r < 4; ++r)
      p2t[16 * w + 4 * kh + r][16 * cb + col] = a2[cb][r];
  __syncthreads();

  float* dst = ATOMIC ? dstG + (size_t)b * 4096
                      : dstG + ((size_t)(b * NBLK_G + blk)) * 4096;
#pragma unroll
  for (int cb = 0; cb < 4; ++cb) {
#pragma unroll
    for (int r = 0; r < 4; ++r) {
      const int R = 16 * w + 4 * kh + r;
      const int C = 16 * cb + col;
      const float vsum = a1[cb][r] + a2[cb][r] + p2t[C][R];
      if (ATOMIC) atomicAdd(&dst[R * 64 + C], vsum);
      else        dst[R * 64 + C] = vsum;
    }
  }
}

// G[b][e] = sum over 200 per-block partials (coalesced across lanes)
__global__ void k_reduceG(const float* __restrict__ partG, float* __restrict__ G) {
  const int el = blockIdx.x * 256 + threadIdx.x;  // 0..16383
  const int b = el >> 12;
  const int e = el & 4095;
  const float* p = partG + (size_t)b * NBLK_G * 4096 + e;
  float s = 0.f;
#pragma unroll 8
  for (int q = 0; q < NBLK_G; ++q) s += p[(size_t)q * 4096];
  G[el] = s;
}

// ---------------------------------------------------------------------------
// One wave per (batch, row r in 0..127): T_row = W[r] @ G ; norm^2 = T_row.W[r]
// ---------------------------------------------------------------------------
__global__ void k_rows(const float* __restrict__ W, const float* __restrict__ G,
                       float* __restrict__ T1, float* __restrict__ inv) {
  const int r = blockIdx.x;
  const int b = blockIdx.y;
  const int lane = threadIdx.x;  // 64
  const float* Wr = W + r * 64;
  const float* Gb = G + (size_t)b * 4096;
  float acc = 0.f;
#pragma unroll 8
  for (int c = 0; c < 64; ++c) acc = fmaf(Wr[c], Gb[c * 64 + lane], acc);
  float p = acc * Wr[lane];
#pragma unroll
  for (int m = 1; m < 64; m <<= 1) p += __shfl_xor(p, m, 64);
  const float nrm = sqrtf(fmaxf(p, 0.f));
  const float iv = 1.f / fmaxf(nrm, 1e-12f);
  if (r < 64) T1[((size_t)b * 64 + r) * 64 + lane] = acc * iv;
  if (lane == 0) inv[b * 128 + r] = iv;
}

// ---------------------------------------------------------------------------
// Per (batch, 16-row quadrant): att = softmax(T1 Wk^T * inv_k); MT[c][d]=(att Wv)^T
// ---------------------------------------------------------------------------
__global__ void k_att(const float* __restrict__ W, const float* __restrict__ T1,
                      const float* __restrict__ inv, float* __restrict__ MT) {
  __shared__ float WkT[64][65];
  __shared__ float T1s[16][64];
  __shared__ float att[16][64];
  const int b = blockIdx.y;
  const int d0 = blockIdx.x * 16;
  const int tid = threadIdx.x;
  const int w = tid >> 6;
  const int lane = tid & 63;

#pragma unroll
  for (int r = 0; r < 16; ++r) {
    const int e = w + 4 * r;
    WkT[lane][e] = W[(64 + e) * 64 + lane];
  }
#pragma unroll
  for (int r = 0; r < 4; ++r) {
    const int dd = w + 4 * r;
    T1s[dd][lane] = T1[((size_t)b * 64 + d0 + dd) * 64 + lane];
  }
  __syncthreads();

  const float invk = inv[b * 128 + 64 + lane];
  float a[4];
#pragma unroll
  for (int it = 0; it < 4; ++it) {
    const int dd = 4 * w + it;
    float s = 0.f;
#pragma unroll 8
    for (int c = 0; c < 64; ++c) s = fmaf(T1s[dd][c], WkT[c][lane], s);
    a[it] = s * invk;
  }
#pragma unroll
  for (int it = 0; it < 4; ++it) {
    float m = a[it];
#pragma unroll
    for (int k = 1; k < 64; k <<= 1) m = fmaxf(m, __shfl_xor(m, k, 64));
    const float e = expf(a[it] - m);
    float s = e;
#pragma unroll
    for (int k = 1; k < 64; k <<= 1) s += __shfl_xor(s, k, 64);
    att[4 * w + it][lane] = e / s;
  }
  __syncthreads();
#pragma unroll
  for (int it = 0; it < 4; ++it) {
    const int dd = 4 * w + it;
    float m = 0.f;
#pragma unroll 8
    for (int e = 0; e < 64; ++e) m = fmaf(att[dd][e], W[(128 + e) * 64 + lane], m);
    MT[(size_t)b * 4096 + lane * 64 + (d0 + dd)] = m;
  }
}

// ---------------------------------------------------------------------------
// k_out: out[d][t] = sum_c MT[c][d] * x[c][t], fp32 VALU at its 21us floor.
// Linear [64][64] LDS x-tile via global_load_lds (dbuf). Lane (dg=l&15,tg=l>>4)
// owns 4d x 4t. Per c: A = MT[c][4dg..] -> ONE coalesced 256B L1 fetch per wave
// (4-way dup); B = tile[c][16w+4tg..] -> 4 distinct addrs x 16-way broadcast
// (conflict-free). LDS pipe ~16 cyc/c vs VALU 32 cyc/c -> VALU-bound.
// ---------------------------------------------------------------------------
__device__ __forceinline__ void stage_lin(const float* __restrict__ xrow0,
                                          float* tile, int w, int lane) {
#pragma unroll
  for (int k = 0; k < 4; ++k) {
    const int chunk = w * 4 + k;
    const int r = chunk * 4 + (lane >> 4);
    const float* g = xrow0 + (size_t)r * NTOK + 4 * (lane & 15);
    float* l = tile + chunk * 256;
    __builtin_amdgcn_global_load_lds((const __attribute__((address_space(1))) void*)g,
                                     (__attribute__((address_space(3))) void*)l,
                                     16, 0, 0);
  }
}

#define VM_WAIT0() do { \
    asm volatile("s_waitcnt vmcnt(0)" ::: "memory"); \
    __builtin_amdgcn_sched_barrier(0); \
    __builtin_amdgcn_s_barrier(); \
  } while (0)

__global__ __launch_bounds__(256, 4) void k_out(const float* __restrict__ x,
                                                const float* __restrict__ MT,
                                                float* __restrict__ out) {
  __shared__ float tiles[2][4096];
  const int b = blockIdx.y, blk = blockIdx.x;
  const int tid = threadIdx.x, w = tid >> 6, lane = tid & 63;
  const int dg = lane & 15, tg = lane >> 4;

  const float* xb = x + (size_t)b * CH * NTOK;
  const float* MTb = MT + (size_t)b * 4096;
  float* ob = out + (size_t)b * DIM * NTOK;
  const int t0 = blk * (TILES_PER_BLK * 64);
  const int tof = 16 * w + 4 * tg;

  stage_lin(xb + t0, tiles[0], w, lane);
  VM_WAIT0();

#pragma unroll 1
  for (int i = 0; i < TILES_PER_BLK; ++i) {
    if (i + 1 < TILES_PER_BLK)
      stage_lin(xb + t0 + 64 * (i + 1), tiles[(i + 1) & 1], w, lane);
    const float* tb = tiles[i & 1];

    float acc[4][4] = {};
#pragma unroll 8
    for (int c = 0; c < 64; ++c) {
      const float4 Am = *(const float4*)(MTb + c * 64 + 4 * dg);
      const float4 Bx = *(const float4*)&tb[c * 64 + tof];
      const float am[4] = {Am.x, Am.y, Am.z, Am.w};
      const float bx[4] = {Bx.x, Bx.y, Bx.z, Bx.w};
#pragma unroll
      for (int u = 0; u < 4; ++u)
#pragma unroll
        for (int v = 0; v < 4; ++v) acc[u][v] = fmaf(am[u], bx[v], acc[u][v]);
    }

    const int tt = t0 + 64 * i + tof;
#pragma unroll
    for (int u = 0; u < 4; ++u) {
      *(float4*)(ob + (size_t)(4 * dg + u) * NTOK + tt) =
          make_float4(acc[u][0], acc[u][1], acc[u][2], acc[u][3]);
    }
    VM_WAIT0();
  }
}

extern "C" void kernel_launch(void* const* d_in, const int* in_sizes, int n_in,
                              void* d_out, int out_size, void* d_ws, size_t ws_size,
                              hipStream_t stream) {
  const float* x = (const float*)d_in[0];
  const float* W = (const float*)d_in[1];
  float* out = (float*)d_out;
  float* ws = (float*)d_ws;

  if (ws_size >= WS_FLOATS_FULL * sizeof(float)) {
    float* partG = ws + OFF_PART;
    float* G = ws + OFF_G;
    float* T1 = ws + OFF_T1;
    float* inv = ws + OFF_INV;
    float* MT = ws + OFF_MT;
    k_gram<false><<<dim3(NBLK_G, BATCH), 256, 0, stream>>>(x, partG);
    k_reduceG<<<dim3(64), 256, 0, stream>>>(partG, G);
    k_rows<<<dim3(128, BATCH), 64, 0, stream>>>(W, G, T1, inv);
    k_att<<<dim3(4, BATCH), 256, 0, stream>>>(W, T1, inv, MT);
    k_out<<<dim3(GBLK_OUT, BATCH), 256, 0, stream>>>(x, MT, out);
  } else {
    float* G = ws + SOFF_G;
    float* T1 = ws + SOFF_T1;
    float* inv = ws + SOFF_INV;
    float* MT = ws + SOFF_MT;
    k_zero<<<dim3(64), 256, 0, stream>>>(G, BATCH * 4096);
    k_gram<true><<<dim3(NBLK_G, BATCH), 256, 0, stream>>>(x, G);
    k_rows<<<dim3(128, BATCH), 64, 0, stream>>>(W, G, T1, inv);
    k_att<<<dim3(4, BATCH), 256, 0, stream>>>(W, T1, inv, MT);
    k_out<<<dim3(GBLK_OUT, BATCH), 256, 0, stream>>>(x, MT, out);
  }
}

// Round 8
// 275.158 us; speedup vs baseline: 1.3196x; 1.0352x over previous
//
#include <hip/hip_runtime.h>
#include <hip/hip_bf16.h>

// FrequencyAttention:
//   G = X X^T (per batch, 64x64)            -> k_gram (MFMA bf16 hi/lo split) + k_reduceG
//   T1 = inv_q * (Wq G); norms via diag     -> k_rows
//   att = softmax(T1 Wk^T * inv_k); M=att Wv-> k_att
//   out = M X                               -> k_out (LDS-free: lane=token, wave-uniform M)
// B=4, C=64, N=102400, D=64. W rows: [0:64]=Wq, [64:128]=Wk, [128:192]=Wv.

#define BATCH 4
#define CH 64
#define NTOK 102400
#define DIM 64

#define NBLK_G 200          // gram blocks per batch
#define TOK_PER_G 512       // tokens per gram block = 8 tiles of 64

// workspace layout (floats)
static const size_t OFF_PART = 0;                                    // [4*200][4096]
static const size_t OFF_G    = (size_t)BATCH * NBLK_G * 4096;        // [4][4096]
static const size_t OFF_T1   = OFF_G  + (size_t)BATCH * 4096;        // [4][64][64]
static const size_t OFF_INV  = OFF_T1 + (size_t)BATCH * 4096;        // [4][128]
static const size_t OFF_MT   = OFF_INV + (size_t)BATCH * 128;        // [4][64][64] ([c][d])
static const size_t WS_FLOATS_FULL = OFF_MT + (size_t)BATCH * 4096;

// small-ws fallback (atomic G accumulation)
static const size_t SOFF_G   = 0;
static const size_t SOFF_T1  = (size_t)BATCH * 4096;
static const size_t SOFF_INV = SOFF_T1 + (size_t)BATCH * 4096;
static const size_t SOFF_MT  = SOFF_INV + (size_t)BATCH * 128;

typedef __attribute__((ext_vector_type(8))) short short8v;
typedef __attribute__((ext_vector_type(4))) float f32x4;

__global__ void k_zero(float* __restrict__ p, int n) {
  int i = blockIdx.x * blockDim.x + threadIdx.x;
  if (i < n) p[i] = 0.f;
}

__device__ __forceinline__ short f2bf(float f) {  // RNE fp32->bf16 bits
  unsigned u = __builtin_bit_cast(unsigned, f);
  unsigned r = (u + 0x7fffu + ((u >> 16) & 1u)) >> 16;
  return (short)r;
}
__device__ __forceinline__ float bf2f(short s) {
  unsigned u = ((unsigned)(unsigned short)s) << 16;
  return __builtin_bit_cast(float, u);
}

// ---------------------------------------------------------------------------
// k_gram: 256 thr / 4 waves. Tile = [64 ch][64 tok] as hi/lo bf16 in LDS,
// double-buffered, granule(16B=8tok)-XOR swizzled: slot = g ^ (row&7).
// Wave w = A-rowblock; 16 MFMA (2 kc x 4 cb x hi/lo) per tile.
// Epilogue: P2^T via padded LDS transpose; store P1+P2+P2^T partial per block.
// ---------------------------------------------------------------------------
template <bool ATOMIC>
__global__ __launch_bounds__(256, 3) void k_gram(const float* __restrict__ x,
                                                 float* __restrict__ dstG) {
  __shared__ short his[2][4096];
  __shared__ short los[2][4096];
  __shared__ float p2t[64][65];
  const int b = blockIdx.y, blk = blockIdx.x;
  const int tid = threadIdx.x;
  const int w = tid >> 6, lane = tid & 63;
  const int col = lane & 15, kh = lane >> 4;   // frag column / k-half
  const int cs = tid >> 2, tq = tid & 3;       // staging: channel, token-quarter

  const float* xb = x + (size_t)b * CH * NTOK;
  const int t0 = blk * TOK_PER_G;

  f32x4 a1[4], a2[4];
#pragma unroll
  for (int cb = 0; cb < 4; ++cb)
#pragma unroll
    for (int r = 0; r < 4; ++r) { a1[cb][r] = 0.f; a2[cb][r] = 0.f; }

  const int sbase = cs * 64;
  const int s0 = ((2 * tq) ^ (cs & 7)) << 3;
  const int s1 = ((2 * tq + 1) ^ (cs & 7)) << 3;

  // prologue: stage tile 0
  {
    const float* src = xb + (size_t)cs * NTOK + t0 + 16 * tq;
    float4 v0 = *(const float4*)(src);
    float4 v1 = *(const float4*)(src + 4);
    float4 v2 = *(const float4*)(src + 8);
    float4 v3 = *(const float4*)(src + 12);
    float f[16] = {v0.x, v0.y, v0.z, v0.w, v1.x, v1.y, v1.z, v1.w,
                   v2.x, v2.y, v2.z, v2.w, v3.x, v3.y, v3.z, v3.w};
    short8v h01, h23, l01, l23;
#pragma unroll
    for (int j = 0; j < 8; ++j) {
      short h = f2bf(f[j]);     h01[j] = h; l01[j] = f2bf(f[j] - bf2f(h));
      short g = f2bf(f[j + 8]); h23[j] = g; l23[j] = f2bf(f[j + 8] - bf2f(g));
    }
    *(short8v*)&his[0][sbase + s0] = h01;
    *(short8v*)&his[0][sbase + s1] = h23;
    *(short8v*)&los[0][sbase + s0] = l01;
    *(short8v*)&los[0][sbase + s1] = l23;
  }
  __syncthreads();

#pragma unroll 1
  for (int i = 0; i < TOK_PER_G / 64; ++i) {
    const int cur = i & 1;
    const bool more = (i + 1) < TOK_PER_G / 64;
    float4 n0, n1, n2, n3;
    if (more) {  // issue next-tile global loads early (latency hides under MFMA)
      const float* src = xb + (size_t)cs * NTOK + t0 + (i + 1) * 64 + 16 * tq;
      n0 = *(const float4*)(src);
      n1 = *(const float4*)(src + 4);
      n2 = *(const float4*)(src + 8);
      n3 = *(const float4*)(src + 12);
    }
    const short* hp = his[cur];
    const short* lp = los[cur];
#pragma unroll
    for (int kc = 0; kc < 2; ++kc) {
      const int g = kc * 4 + kh;
      const int rA = 16 * w + col;
      const short8v A = *(const short8v*)&hp[rA * 64 + ((g ^ (rA & 7)) << 3)];
#pragma unroll
      for (int cb = 0; cb < 4; ++cb) {
        const int rB = 16 * cb + col;
        const int off = rB * 64 + ((g ^ (rB & 7)) << 3);
        const short8v Bh = *(const short8v*)&hp[off];
        const short8v Bl = *(const short8v*)&lp[off];
        a1[cb] = __builtin_amdgcn_mfma_f32_16x16x32_bf16(A, Bh, a1[cb], 0, 0, 0);
        a2[cb] = __builtin_amdgcn_mfma_f32_16x16x32_bf16(A, Bl, a2[cb], 0, 0, 0);
      }
    }
    if (more) {
      const int nxt = cur ^ 1;
      float f[16] = {n0.x, n0.y, n0.z, n0.w, n1.x, n1.y, n1.z, n1.w,
                     n2.x, n2.y, n2.z, n2.w, n3.x, n3.y, n3.z, n3.w};
      short8v h01, h23, l01, l23;
#pragma unroll
      for (int j = 0; j < 8; ++j) {
        short h = f2bf(f[j]);     h01[j] = h; l01[j] = f2bf(f[j] - bf2f(h));
        short g2 = f2bf(f[j + 8]); h23[j] = g2; l23[j] = f2bf(f[j + 8] - bf2f(g2));
      }
      *(short8v*)&his[nxt][sbase + s0] = h01;
      *(short8v*)&his[nxt][sbase + s1] = h23;
      *(short8v*)&los[nxt][sbase + s0] = l01;
      *(short8v*)&los[nxt][sbase + s1] = l23;
    }
    __syncthreads();
  }

  // epilogue: fold P2^T. C/D layout (verified m89/m91): col=lane&15, row=(lane>>4)*4+reg.
#pragma unroll
  for (int cb = 0; cb < 4; ++cb)
#pragma unroll
    for (int r = 0; r < 4; ++r)
      p2t[16 * w + 4 * kh + r][16 * cb + col] = a2[cb][r];
  __syncthreads();

  float* dst = ATOMIC ? dstG + (size_t)b * 4096
                      : dstG + ((size_t)(b * NBLK_G + blk)) * 4096;
#pragma unroll
  for (int cb = 0; cb < 4; ++cb) {
#pragma unroll
    for (int r = 0; r < 4; ++r) {
      const int R = 16 * w + 4 * kh + r;
      const int C = 16 * cb + col;
      const float vsum = a1[cb][r] + a2[cb][r] + p2t[C][R];
      if (ATOMIC) atomicAdd(&dst[R * 64 + C], vsum);
      else        dst[R * 64 + C] = vsum;
    }
  }
}

// G[b][e] = sum over 200 per-block partials; 256 blocks x 64 thr spreads CUs
__global__ void k_reduceG(const float* __restrict__ partG, float* __restrict__ G) {
  const int el = blockIdx.x * 64 + threadIdx.x;  // 0..16383
  const int b = el >> 12;
  const int e = el & 4095;
  const float* p = partG + (size_t)b * NBLK_G * 4096 + e;
  float s = 0.f;
#pragma unroll 8
  for (int q = 0; q < NBLK_G; ++q) s += p[(size_t)q * 4096];
  G[el] = s;
}

// ---------------------------------------------------------------------------
// One wave per (batch, row r in 0..127): T_row = W[r] @ G ; norm^2 = T_row.W[r]
// ---------------------------------------------------------------------------
__global__ void k_rows(const float* __restrict__ W, const float* __restrict__ G,
                       float* __restrict__ T1, float* __restrict__ inv) {
  const int r = blockIdx.x;
  const int b = blockIdx.y;
  const int lane = threadIdx.x;  // 64
  const float* Wr = W + r * 64;
  const float* Gb = G + (size_t)b * 4096;
  float acc = 0.f;
#pragma unroll 8
  for (int c = 0; c < 64; ++c) acc = fmaf(Wr[c], Gb[c * 64 + lane], acc);
  float p = acc * Wr[lane];
#pragma unroll
  for (int m = 1; m < 64; m <<= 1) p += __shfl_xor(p, m, 64);
  const float nrm = sqrtf(fmaxf(p, 0.f));
  const float iv = 1.f / fmaxf(nrm, 1e-12f);
  if (r < 64) T1[((size_t)b * 64 + r) * 64 + lane] = acc * iv;
  if (lane == 0) inv[b * 128 + r] = iv;
}

// ---------------------------------------------------------------------------
// Per (batch, 16-row quadrant): att = softmax(T1 Wk^T * inv_k); MT[c][d]=(att Wv)^T
// ---------------------------------------------------------------------------
__global__ void k_att(const float* __restrict__ W, const float* __restrict__ T1,
                      const float* __restrict__ inv, float* __restrict__ MT) {
  __shared__ float WkT[64][65];
  __shared__ float T1s[16][64];
  __shared__ float att[16][64];
  const int b = blockIdx.y;
  const int d0 = blockIdx.x * 16;
  const int tid = threadIdx.x;
  const int w = tid >> 6;
  const int lane = tid & 63;

#pragma unroll
  for (int r = 0; r < 16; ++r) {
    const int e = w + 4 * r;
    WkT[lane][e] = W[(64 + e) * 64 + lane];
  }
#pragma unroll
  for (int r = 0; r < 4; ++r) {
    const int dd = w + 4 * r;
    T1s[dd][lane] = T1[((size_t)b * 64 + d0 + dd) * 64 + lane];
  }
  __syncthreads();

  const float invk = inv[b * 128 + 64 + lane];
  float a[4];
#pragma unroll
  for (int it = 0; it < 4; ++it) {
    const int dd = 4 * w + it;
    float s = 0.f;
#pragma unroll 8
    for (int c = 0; c < 64; ++c) s = fmaf(T1s[dd][c], WkT[c][lane], s);
    a[it] = s * invk;
  }
#pragma unroll
  for (int it = 0; it < 4; ++it) {
    float m = a[it];
#pragma unroll
    for (int k = 1; k < 64; k <<= 1) m = fmaxf(m, __shfl_xor(m, k, 64));
    const float e = expf(a[it] - m);
    float s = e;
#pragma unroll
    for (int k = 1; k < 64; k <<= 1) s += __shfl_xor(s, k, 64);
    att[4 * w + it][lane] = e / s;
  }
  __syncthreads();
#pragma unroll
  for (int it = 0; it < 4; ++it) {
    const int dd = 4 * w + it;
    float m = 0.f;
#pragma unroll 8
    for (int e = 0; e < 64; ++e) m = fmaf(att[dd][e], W[(128 + e) * 64 + lane], m);
    MT[(size_t)b * 4096 + lane * 64 + (d0 + dd)] = m;
  }
}

// ---------------------------------------------------------------------------
// k_out: out[d][t] = sum_c MT[c][d] * x[c][t]. LDS-FREE. Lane = token: each
// lane accumulates out[0..63][t] in 64 regs. Per c: one coalesced 256B x-load
// per wave (distinct tokens, zero duplication) + wave-uniform M row (MT[c][*]
// contiguous, readfirstlane'd base -> scalar-cache broadcast). No barriers,
// no ds_read, 1 FMA per MAC = 21us VALU floor. 800 blocks all-resident,
// each wave exactly 2 token-blocks (no straggler round).
// ---------------------------------------------------------------------------
__global__ __launch_bounds__(256) void k_out(const float* __restrict__ x,
                                             const float* __restrict__ MT,
                                             float* __restrict__ out) {
  const int wgid = blockIdx.x * 4 + (threadIdx.x >> 6);  // 0..3199
  const int lane = threadIdx.x & 63;

#pragma unroll 1
  for (int rep = 0; rep < 2; ++rep) {
    const int tb = __builtin_amdgcn_readfirstlane(wgid * 2 + rep);  // 0..6399
    const int b = tb / 1600;
    const int t0 = (tb - b * 1600) * 64;
    const float* xb = x + (size_t)b * CH * NTOK + t0 + lane;
    const float* Mb = MT + (size_t)b * 4096;
    float* ob = out + (size_t)b * DIM * NTOK + t0 + lane;

    float acc[64];
#pragma unroll
    for (int d = 0; d < 64; ++d) acc[d] = 0.f;

#pragma unroll 4
    for (int c = 0; c < 64; ++c) {
      const float xv = xb[(size_t)c * NTOK];
      const float* Mc = Mb + c * 64;  // M[*][c], contiguous, wave-uniform
#pragma unroll
      for (int d = 0; d < 64; ++d) acc[d] = fmaf(Mc[d], xv, acc[d]);
    }

#pragma unroll
    for (int d = 0; d < 64; ++d) ob[(size_t)d * NTOK] = acc[d];
  }
}

extern "C" void kernel_launch(void* const* d_in, const int* in_sizes, int n_in,
                              void* d_out, int out_size, void* d_ws, size_t ws_size,
                              hipStream_t stream) {
  const float* x = (const float*)d_in[0];
  const float* W = (const float*)d_in[1];
  float* out = (float*)d_out;
  float* ws = (float*)d_ws;

  if (ws_size >= WS_FLOATS_FULL * sizeof(float)) {
    float* partG = ws + OFF_PART;
    float* G = ws + OFF_G;
    float* T1 = ws + OFF_T1;
    float* inv = ws + OFF_INV;
    float* MT = ws + OFF_MT;
    k_gram<false><<<dim3(NBLK_G, BATCH), 256, 0, stream>>>(x, partG);
    k_reduceG<<<dim3(256), 64, 0, stream>>>(partG, G);
    k_rows<<<dim3(128, BATCH), 64, 0, stream>>>(W, G, T1, inv);
    k_att<<<dim3(4, BATCH), 256, 0, stream>>>(W, T1, inv, MT);
    k_out<<<dim3(800), 256, 0, stream>>>(x, MT, out);
  } else {
    float* G = ws + SOFF_G;
    float* T1 = ws + SOFF_T1;
    float* inv = ws + SOFF_INV;
    float* MT = ws + SOFF_MT;
    k_zero<<<dim3(64), 256, 0, stream>>>(G, BATCH * 4096);
    k_gram<true><<<dim3(NBLK_G, BATCH), 256, 0, stream>>>(x, G);
    k_rows<<<dim3(128, BATCH), 64, 0, stream>>>(W, G, T1, inv);
    k_att<<<dim3(4, BATCH), 256, 0, stream>>>(W, T1, inv, MT);
    k_out<<<dim3(800), 256, 0, stream>>>(x, MT, out);
  }
}